// Round 3
// baseline (244.621 us; speedup 1.0000x reference)
//
#include <hip/hip_runtime.h>
#include <hip/hip_bf16.h>

// Problem constants
#define NTOK 32768
#define CH   256
#define NEXP 16

typedef __attribute__((ext_vector_type(8)))  short short8;   // 8 x bf16 (4 VGPR)
typedef __attribute__((ext_vector_type(16))) float f32x16;   // MFMA 32x32 accumulator

#define MFMA32(a, b, c) __builtin_amdgcn_mfma_f32_32x32x16_bf16((a), (b), (c), 0, 0, 0)
#define BC8(v) __builtin_bit_cast(short8, (v))

// async global->LDS, 16B per lane; lds ptr must be wave-uniform (dst = base + lane*16)
#define GLD16(lds, g) __builtin_amdgcn_global_load_lds(                          \
    (const __attribute__((address_space(1))) unsigned int*)(g),                  \
    (__attribute__((address_space(3))) unsigned int*)(lds), 16, 0, 0)

// fp32 -> bf16 round-to-nearest-even
static __device__ __forceinline__ unsigned short f2bf(float f) {
  unsigned int u = __builtin_bit_cast(unsigned int, f);
  unsigned int r = (u + 0x7fffu + ((u >> 16) & 1u)) >> 16;
  return (unsigned short)r;
}

// ---------------------------------------------------------------------------
// Workspace layout (bytes):
//   [0,        16777216)  A_packed   N*C bf16, MFMA A-fragment order, per 64-tok tile
//   [16777216, 19005440)  W_packed   17*C*C bf16, MFMA B-fragment order
//   [19005440, 21102592)  combine    N*16 fp32
//   [21102592, 21168128)  frac_part  512*32 fp32
// ---------------------------------------------------------------------------

// Kernel 1: share_W (expert 16) + expert_W -> bf16 B-fragment order:
//   line (e, db, kb, lane) holds B[k = kb*16 + (lane>>5)*8 + j][d = db*32 + (lane&31)]
__global__ __launch_bounds__(256) void wconvert_kernel(
    const float* __restrict__ share_W, const float* __restrict__ expert_W,
    uint4* __restrict__ wp) {
  int g = blockIdx.x * 256 + threadIdx.x;   // 17*8192 lines
  int e = g >> 13;
  int r = g & 8191;
  int lane = r & 63;
  int kb = (r >> 6) & 15;
  int db = r >> 10;
  int d  = db * 32 + (lane & 31);
  int k0 = kb * 16 + ((lane >> 5) << 3);
  const float* src = (e < 16) ? (expert_W + (size_t)e * 65536) : share_W;
  unsigned int p[4];
#pragma unroll
  for (int j = 0; j < 4; j++) {
    float f0 = src[(size_t)(k0 + 2 * j) * 256 + d];
    float f1 = src[(size_t)(k0 + 2 * j + 1) * 256 + d];
    p[j] = (unsigned int)f2bf(f0) | ((unsigned int)f2bf(f1) << 16);
  }
  wp[g] = make_uint4(p[0], p[1], p[2], p[3]);
}

// Kernel 2 (R3 = R2 design, launch_bounds relaxed to (512,2) to remove VGPR
// spill risk — LDS (57.9 KB) already caps occupancy at 2 blocks/CU):
// 512 threads = 8 waves x 8 tokens; gate_W quarter hoisted into 16 float4
// VGPRs per lane; dot accumulator split 4-way.
__global__ __launch_bounds__(512, 2) void gate_kernel(
    const float* __restrict__ inputs, const float* __restrict__ conv_out,
    const float* __restrict__ domain_emb, const float* __restrict__ gate_W,
    const float* __restrict__ gate_b, const float* __restrict__ ln_gamma,
    const float* __restrict__ ln_beta, uint4* __restrict__ apack,
    float* __restrict__ combine, float* __restrict__ frac_part) {
  __shared__ __align__(16) unsigned short atile[64 * 256]; // 32 KB xor-swizzled
  __shared__ __align__(16) float gwT[16 * 260];            // [e][c], pad 260
  __shared__ float route[8][256];                          // per-wave private rows
  __shared__ float fred[2][8][16];
  int t = threadIdx.x, b = blockIdx.x;
  int w = t >> 6, l = t & 63;

  // stage gate_W transposed: gwT[e*260 + c] = gate_W[c*16 + e]
  for (int i = 0; i < 8; i++) {
    int idx = i * 512 + t;
    gwT[(idx & 15) * 260 + (idx >> 4)] = gate_W[idx];
  }

  for (int i = 0; i < 4; i++) {
    int idx = i * 512 + t;
    int row = idx >> 5;
    int j = idx & 31;
    const float4* src = (const float4*)(inputs + ((size_t)b * 64 + row) * 256 + j * 8);
    float4 f0 = src[0], f1 = src[1];
    unsigned int p0 = (unsigned int)f2bf(f0.x) | ((unsigned int)f2bf(f0.y) << 16);
    unsigned int p1 = (unsigned int)f2bf(f0.z) | ((unsigned int)f2bf(f0.w) << 16);
    unsigned int p2 = (unsigned int)f2bf(f1.x) | ((unsigned int)f2bf(f1.y) << 16);
    unsigned int p3 = (unsigned int)f2bf(f1.z) | ((unsigned int)f2bf(f1.w) << 16);
    int s = j ^ (row & 31);
    *(uint4*)(atile + (row * 32 + s) * 8) = make_uint4(p0, p1, p2, p3);
  }
  __syncthreads();
  for (int i = 0; i < 4; i++) {
    int L = i * 512 + t;
    int ll = L & 63;
    int mb = (L >> 6) & 1, kb = L >> 7;
    int row = mb * 32 + (ll & 31);
    int j = kb * 2 + (ll >> 5);
    int s = j ^ (row & 31);
    apack[(size_t)b * 2048 + L] = *(const uint4*)(atile + (row * 32 + s) * 8);
  }

  int lc = l * 4;
  float4 g4 = *(const float4*)(ln_gamma + lc);
  float4 be4 = *(const float4*)(ln_beta + lc);
  float4 de4 = *(const float4*)(domain_emb + lc);
  int e = l & 15, q = l >> 4;
  float gb = gate_b[e];
  float psel = 0.f, pw = 0.f;

  // hoist this lane's gate-weight quarter into registers (gwT staged above,
  // __syncthreads already passed)
  float4 gwreg[16];
#pragma unroll
  for (int ii = 0; ii < 16; ii++)
    gwreg[ii] = *(const float4*)&gwT[e * 260 + q * 64 + ii * 4];

  int n0 = b * 64 + w * 8;
  float4 x = *(const float4*)(conv_out + (size_t)n0 * 256 + lc);
  for (int i = 0; i < 8; i++) {
    // prefetch next token's row (wraps at i==7; value unused)
    float4 xn = *(const float4*)(conv_out + (size_t)(n0 + ((i + 1) & 7)) * 256 + lc);

    float s1 = x.x + x.y + x.z + x.w;
#pragma unroll
    for (int off = 1; off < 64; off <<= 1) s1 += __shfl_xor(s1, off);
    float mu = s1 * (1.f / 256.f);
    float dx = x.x - mu, dy = x.y - mu, dz = x.z - mu, dw = x.w - mu;
    float s2 = dx * dx + dy * dy + dz * dz + dw * dw;
#pragma unroll
    for (int off = 1; off < 64; off <<= 1) s2 += __shfl_xor(s2, off);
    float rstd = rsqrtf(s2 * (1.f / 256.f) + 1e-5f);
    float4 r;
    r.x = dx * rstd * g4.x + be4.x + de4.x;
    r.y = dy * rstd * g4.y + be4.y + de4.y;
    r.z = dz * rstd * g4.z + be4.z + de4.z;
    r.w = dw * rstd * g4.w + be4.w + de4.w;
    *(float4*)(&route[w][lc]) = r;
    // route[w] is wave-private: wave-local fence instead of block barrier
    asm volatile("s_waitcnt lgkmcnt(0)" ::: "memory");
    __builtin_amdgcn_wave_barrier();

    // logit: lane (q,e) dots channels [q*64, q*64+64) against reg-resident gw
    float a0 = 0.f, a1 = 0.f, a2 = 0.f, a3 = 0.f;
#pragma unroll
    for (int ii = 0; ii < 16; ii += 4) {
      float4 r0 = *(const float4*)(&route[w][q * 64 + (ii + 0) * 4]);
      float4 r1 = *(const float4*)(&route[w][q * 64 + (ii + 1) * 4]);
      float4 r2 = *(const float4*)(&route[w][q * 64 + (ii + 2) * 4]);
      float4 r3 = *(const float4*)(&route[w][q * 64 + (ii + 3) * 4]);
      a0 += r0.x * gwreg[ii + 0].x + r0.y * gwreg[ii + 0].y + r0.z * gwreg[ii + 0].z + r0.w * gwreg[ii + 0].w;
      a1 += r1.x * gwreg[ii + 1].x + r1.y * gwreg[ii + 1].y + r1.z * gwreg[ii + 1].z + r1.w * gwreg[ii + 1].w;
      a2 += r2.x * gwreg[ii + 2].x + r2.y * gwreg[ii + 2].y + r2.z * gwreg[ii + 2].z + r2.w * gwreg[ii + 2].w;
      a3 += r3.x * gwreg[ii + 3].x + r3.y * gwreg[ii + 3].y + r3.z * gwreg[ii + 3].z + r3.w * gwreg[ii + 3].w;
    }
    float acc = (a0 + a1) + (a2 + a3);
    acc += __shfl_xor(acc, 16);
    acc += __shfl_xor(acc, 32);
    float logit = acc + gb;

    float m = logit;
#pragma unroll
    for (int off = 1; off < 16; off <<= 1) m = fmaxf(m, __shfl_xor(m, off));
    float p = expf(logit - m);
    float sum = p;
#pragma unroll
    for (int off = 1; off < 16; off <<= 1) sum += __shfl_xor(sum, off);
    float wv = p / sum;

    float et = -wv * logf(wv + 1e-12f);
    float ent = et;
#pragma unroll
    for (int off = 1; off < 16; off <<= 1) ent += __shfl_xor(ent, off);
    float kf = ceilf(1.f + ent * (15.f / 2.7725887f));
    int k = (int)kf;
    k = max(1, min(16, k));

    int base = l & 48;
    int rank = 0;
#pragma unroll
    for (int j = 0; j < 16; j++) {
      float wj = __shfl(wv, base + j);
      rank += (wj > wv) || (wj == wv && j < e);
    }
    int sel = rank < k;
    float cmb = sel ? wv : 0.f;
    int n = n0 + i;
    if (l < 16) combine[(size_t)n * 16 + e] = cmb;
    psel += (float)sel;
    pw += wv;

    x = xn;
  }

  if (l < 16) { fred[0][w][l] = psel; fred[1][w][l] = pw; }
  __syncthreads();
  if (t < 32) {
    int kind = t >> 4, ee = t & 15;
    float v = 0.f;
#pragma unroll
    for (int ww = 0; ww < 8; ww++) v += fred[kind][ww][ee];
    frac_part[b * 32 + t] = v;
  }
}

// Kernel 3 (v5): same tiling as v4 (128 tok x 256 col, 8 waves, e-outer/
// q-inner, double-buffered B via global_load_lds). R2 change: the sync
// structure. __syncthreads (which drains vmcnt(0) — the m97-class ~20%
// stall; we measured MfmaUtil pinned at 37.6% = that structure's ceiling)
// is replaced by the counted-vmcnt two-barrier pattern (T4):
//   fence; s_barrier;            // compute(s-1) reads done -> buf writable
//   prefetch(s+1); vmcnt(4);     // my slot-s loads landed; s+1's stay in flight
//   s_barrier; fence;            // all waves' slot-s loads landed
//   compute(s)                   // MFMA cluster wrapped in setprio (T5)
// No vmcnt(0) in the main loop (only last slot).
__global__ __launch_bounds__(512, 2) void moe_gemm_kernel(
    const uint4* __restrict__ apack, const uint4* __restrict__ wpack,
    const float* __restrict__ combine, const float* __restrict__ expert_b,
    const float* __restrict__ share_b, float* __restrict__ out) {
  extern __shared__ __align__(16) char smem[];
  uint4* atile  = (uint4*)smem;               // 4096 uint4 = 64 KB
  uint4* btile0 = (uint4*)(smem + 65536);     // 2048 uint4 = 32 KB
  uint4* btile1 = (uint4*)(smem + 98304);     // 2048 uint4 = 32 KB
  float* wtile  = (float*)(smem + 131072);    // [e][row] 16*128 fp32 = 8 KB

  int t = threadIdx.x, b = blockIdx.x;
  int w = t >> 6, l = t & 63;
  int mbp = w >> 2;      // 0..1 -> rows (mbp*2+{0,1})*32
  int dbp = w & 3;       // 0..3 -> cols (dbp*2+{0,1})*32

  // ---- initial stages ----
  // A: 64 line-groups (kb 0..15 x mb 0..3), 8 per wave, from two 64-tok tiles
#pragma unroll
  for (int i = 0; i < 8; i++) {
    int g = w * 8 + i;
    int kb = g >> 2, mb = g & 3;
    const uint4* src = apack + ((size_t)(2 * b + (mb >> 1)) * 2048 + (size_t)(kb * 2 + (mb & 1)) * 64 + l);
    GLD16(atile + g * 64, src);
  }
  // B slot 0 (e=0, q=0) into btile0: 32 line-groups (kbl 0..3 x db 0..7), 4/wave
#pragma unroll
  for (int i = 0; i < 4; i++) {
    int g = w * 4 + i;
    int kbl = g >> 3, db = g & 7;
    GLD16(btile0 + g * 64, wpack + ((size_t)db * 1024 + kbl * 64 + l));
  }
  // wtile transposed stage: combine[tok][e] -> wtile[e*128 + tok]
  {
    const float* cg = combine + (size_t)b * 2048;
#pragma unroll
    for (int i = 0; i < 4; i++) {
      int idx = i * 512 + t;
      wtile[(idx & 15) * 128 + (idx >> 4)] = cg[idx];
    }
  }
  // wtile ds_writes must be globally visible before the first barrier
  asm volatile("s_waitcnt lgkmcnt(0)" ::: "memory");

  f32x16 facc[2][2];
#pragma unroll
  for (int mi = 0; mi < 2; mi++)
#pragma unroll
    for (int d = 0; d < 2; d++)
#pragma unroll
      for (int r = 0; r < 16; r++) facc[mi][d][r] = 0.f;
  f32x16 zc;
#pragma unroll
  for (int r = 0; r < 16; r++) zc[r] = 0.f;

  short8 areg[2][4];
  f32x16 tacc[2][2];
  uint4* bufs[2] = {btile0, btile1};
  int rowoff = (l >> 5) * 4;   // C/D layout row offset for this half-wave

  for (int e = 0; e < 17; e++) {
#pragma unroll
    for (int q = 0; q < 4; q++) {
      int s = e * 4 + q;

      // B1: all waves done with compute(s-1) -> buf[(s+1)&1] is writable
      asm volatile("" ::: "memory");
      __builtin_amdgcn_s_barrier();

      if (s < 67) {
        // async prefetch of next slot's B; counted wait keeps it in flight
        int sn = s + 1;
        int en = sn >> 2, qn = sn & 3;
        uint4* nb = bufs[sn & 1];
#pragma unroll
        for (int i = 0; i < 4; i++) {
          int g = w * 4 + i;
          int kbl = g >> 3, db = g & 7;
          GLD16(nb + g * 64,
                wpack + ((size_t)en * 8192 + (size_t)db * 1024 + (qn * 4 + kbl) * 64 + l));
        }
        asm volatile("s_waitcnt vmcnt(4)" ::: "memory");  // slot-s loads landed
      } else {
        asm volatile("s_waitcnt vmcnt(0)" ::: "memory");  // last slot: drain
      }

      // B2: all waves' slot-s loads landed
      __builtin_amdgcn_s_barrier();
      asm volatile("" ::: "memory");

      // A-frags for this K-quarter (re-read each slot; LDS has BW headroom)
#pragma unroll
      for (int mi = 0; mi < 2; mi++)
#pragma unroll
        for (int kbl = 0; kbl < 4; kbl++)
          areg[mi][kbl] = BC8(atile[((size_t)(q * 4 + kbl) * 4 + (mbp * 2 + mi)) * 64 + l]);

      const uint4* cb = bufs[s & 1];
      __builtin_amdgcn_s_setprio(1);
      if (q == 0) {
        // first quarter of this expert: kbl 0 zero-C init, rest accumulate
        {
          short8 b0 = BC8(cb[(size_t)(0 * 8 + dbp * 2 + 0) * 64 + l]);
          short8 b1 = BC8(cb[(size_t)(0 * 8 + dbp * 2 + 1) * 64 + l]);
          tacc[0][0] = MFMA32(areg[0][0], b0, zc);
          tacc[0][1] = MFMA32(areg[0][0], b1, zc);
          tacc[1][0] = MFMA32(areg[1][0], b0, zc);
          tacc[1][1] = MFMA32(areg[1][0], b1, zc);
        }
#pragma unroll
        for (int kbl = 1; kbl < 4; kbl++) {
          short8 b0 = BC8(cb[(size_t)(kbl * 8 + dbp * 2 + 0) * 64 + l]);
          short8 b1 = BC8(cb[(size_t)(kbl * 8 + dbp * 2 + 1) * 64 + l]);
          tacc[0][0] = MFMA32(areg[0][kbl], b0, tacc[0][0]);
          tacc[0][1] = MFMA32(areg[0][kbl], b1, tacc[0][1]);
          tacc[1][0] = MFMA32(areg[1][kbl], b0, tacc[1][0]);
          tacc[1][1] = MFMA32(areg[1][kbl], b1, tacc[1][1]);
        }
      } else {
        // quarters 1..3: pure accumulation into tacc
#pragma unroll
        for (int kbl = 0; kbl < 4; kbl++) {
          short8 b0 = BC8(cb[(size_t)(kbl * 8 + dbp * 2 + 0) * 64 + l]);
          short8 b1 = BC8(cb[(size_t)(kbl * 8 + dbp * 2 + 1) * 64 + l]);
          tacc[0][0] = MFMA32(areg[0][kbl], b0, tacc[0][0]);
          tacc[0][1] = MFMA32(areg[0][kbl], b1, tacc[0][1]);
          tacc[1][0] = MFMA32(areg[1][kbl], b0, tacc[1][0]);
          tacc[1][1] = MFMA32(areg[1][kbl], b1, tacc[1][1]);
        }
      }
      __builtin_amdgcn_s_setprio(0);

      // scale-add full-K expert output: facc += w[row,e] * tacc (once per expert)
      if (q == 3) {
        if (e < 16) {
#pragma unroll
          for (int mi = 0; mi < 2; mi++)
#pragma unroll
            for (int rg = 0; rg < 4; rg++) {
              float4 w4 = *(const float4*)&wtile[e * 128 + (mbp * 2 + mi) * 32 + 8 * rg + rowoff];
              float wj[4] = {w4.x, w4.y, w4.z, w4.w};
#pragma unroll
              for (int j = 0; j < 4; j++) {
                facc[mi][0][rg * 4 + j] += wj[j] * tacc[mi][0][rg * 4 + j];
                facc[mi][1][rg * 4 + j] += wj[j] * tacc[mi][1][rg * 4 + j];
              }
            }
        } else {  // shared expert, weight 1.0
#pragma unroll
          for (int mi = 0; mi < 2; mi++)
#pragma unroll
            for (int r = 0; r < 16; r++) {
              facc[mi][0][r] += tacc[mi][0][r];
              facc[mi][1][r] += tacc[mi][1][r];
            }
        }
      }
    }
  }

  // ---- final epilogue: bias terms + store ----
  int col = l & 31;
  int cg0 = (dbp * 2 + 0) * 32 + col;
  int cg1 = (dbp * 2 + 1) * 32 + col;
  float sb0 = share_b[cg0], sb1 = share_b[cg1];
  float eb0[16], eb1[16];
#pragma unroll
  for (int e2 = 0; e2 < 16; e2++) {
    eb0[e2] = expert_b[e2 * 256 + cg0];
    eb1[e2] = expert_b[e2 * 256 + cg1];
  }
  // facc += sum_e w[row,e] * expert_b[e,col]
#pragma unroll
  for (int e2 = 0; e2 < 16; e2++)
#pragma unroll
    for (int mi = 0; mi < 2; mi++)
#pragma unroll
      for (int rg = 0; rg < 4; rg++) {
        float4 w4 = *(const float4*)&wtile[e2 * 128 + (mbp * 2 + mi) * 32 + 8 * rg + rowoff];
        float wj[4] = {w4.x, w4.y, w4.z, w4.w};
#pragma unroll
        for (int j = 0; j < 4; j++) {
          facc[mi][0][rg * 4 + j] += wj[j] * eb0[e2];
          facc[mi][1][rg * 4 + j] += wj[j] * eb1[e2];
        }
      }
#pragma unroll
  for (int mi = 0; mi < 2; mi++)
#pragma unroll
    for (int r = 0; r < 16; r++) {
      int row = (mbp * 2 + mi) * 32 + (r & 3) + ((r >> 2) << 3) + rowoff;
      size_t n = (size_t)b * 128 + row;
      out[n * 256 + cg0] = facc[mi][0][r] + sb0;
      out[n * 256 + cg1] = facc[mi][1][r] + sb1;
    }
}

// Kernel 4: reduce balance-loss partials -> scalar at d_out[N*C]
__global__ __launch_bounds__(256) void finalize_kernel(
    const float* __restrict__ frac_part, float* __restrict__ loss_out) {
  __shared__ float acc[8][32];
  int t = threadIdx.x;
  int col = t & 31, seg = t >> 5;
  float s = 0.f;
  for (int i = seg; i < 512; i += 8) s += frac_part[i * 32 + col];
  acc[seg][col] = s;
  __syncthreads();
  if (t < 32) {
    float v = 0.f;
#pragma unroll
    for (int sg = 0; sg < 8; sg++) v += acc[sg][t];
    acc[0][t] = v;
  }
  __syncthreads();
  if (t == 0) {
    float loss = 0.f;
    for (int e = 0; e < 16; e++) {
      float ft = acc[0][e] * (1.f / 32768.f);
      float fp = acc[0][16 + e] * (1.f / 32768.f);
      loss += ft * fp;
    }
    loss_out[0] = loss * 16.f;
  }
}

extern "C" void kernel_launch(void* const* d_in, const int* in_sizes, int n_in,
                              void* d_out, int out_size, void* d_ws, size_t ws_size,
                              hipStream_t stream) {
  const float* inputs   = (const float*)d_in[0];
  const float* conv_out = (const float*)d_in[1];
  const float* demb     = (const float*)d_in[2];
  const float* share_W  = (const float*)d_in[3];
  const float* share_b  = (const float*)d_in[4];
  const float* gate_W   = (const float*)d_in[5];
  const float* gate_b   = (const float*)d_in[6];
  const float* expert_W = (const float*)d_in[7];
  const float* expert_b = (const float*)d_in[8];
  const float* ln_g     = (const float*)d_in[9];
  const float* ln_b     = (const float*)d_in[10];
  float* out = (float*)d_out;
  char* ws = (char*)d_ws;

  uint4* apack   = (uint4*)(ws);
  uint4* wpack   = (uint4*)(ws + 16777216);
  float* combine = (float*)(ws + 19005440);
  float* frac    = (float*)(ws + 21102592);

  // allow 136 KB dynamic LDS (idempotent; not a stream op, safe under capture)
  hipFuncSetAttribute((const void*)moe_gemm_kernel,
                      hipFuncAttributeMaxDynamicSharedMemorySize, 139264);

  wconvert_kernel<<<dim3(544), dim3(256), 0, stream>>>(share_W, expert_W, wpack);
  gate_kernel<<<dim3(512), dim3(512), 0, stream>>>(inputs, conv_out, demb, gate_W,
                                                   gate_b, ln_g, ln_b, apack, combine, frac);
  moe_gemm_kernel<<<dim3(256), dim3(512), 139264, stream>>>(apack, wpack, combine,
                                                            expert_b, share_b, out);
  finalize_kernel<<<dim3(1), dim3(256), 0, stream>>>(frac, out + 8388608);
}

// Round 5
// 240.980 us; speedup vs baseline: 1.0151x; 1.0151x over previous
//
#include <hip/hip_runtime.h>
#include <hip/hip_bf16.h>

// Problem constants
#define NTOK 32768
#define CH   256
#define NEXP 16

typedef __attribute__((ext_vector_type(8)))  short short8;   // 8 x bf16 (4 VGPR)
typedef __attribute__((ext_vector_type(16))) float f32x16;   // MFMA 32x32 accumulator

#define MFMA32(a, b, c) __builtin_amdgcn_mfma_f32_32x32x16_bf16((a), (b), (c), 0, 0, 0)
#define BC8(v) __builtin_bit_cast(short8, (v))

// async global->LDS, 16B per lane; lds ptr must be wave-uniform (dst = base + lane*16)
#define GLD16(lds, g) __builtin_amdgcn_global_load_lds(                          \
    (const __attribute__((address_space(1))) unsigned int*)(g),                  \
    (__attribute__((address_space(3))) unsigned int*)(lds), 16, 0, 0)

// fp32 -> bf16 round-to-nearest-even
static __device__ __forceinline__ unsigned short f2bf(float f) {
  unsigned int u = __builtin_bit_cast(unsigned int, f);
  unsigned int r = (u + 0x7fffu + ((u >> 16) & 1u)) >> 16;
  return (unsigned short)r;
}

// ---------------------------------------------------------------------------
// Workspace layout (bytes):
//   [0,        16777216)  A_packed   N*C bf16, MFMA A-fragment order, per 64-tok tile
//   [16777216, 19005440)  W_packed   17*C*C bf16, MFMA B-fragment order
//   [19005440, 21102592)  combine    N*16 fp32
//   [21102592, 21168128)  frac_part  512*32 fp32
// ---------------------------------------------------------------------------

// Kernel 1: share_W (expert 16) + expert_W -> bf16 B-fragment order:
//   line (e, db, kb, lane) holds B[k = kb*16 + (lane>>5)*8 + j][d = db*32 + (lane&31)]
__global__ __launch_bounds__(256) void wconvert_kernel(
    const float* __restrict__ share_W, const float* __restrict__ expert_W,
    uint4* __restrict__ wp) {
  int g = blockIdx.x * 256 + threadIdx.x;   // 17*8192 lines
  int e = g >> 13;
  int r = g & 8191;
  int lane = r & 63;
  int kb = (r >> 6) & 15;
  int db = r >> 10;
  int d  = db * 32 + (lane & 31);
  int k0 = kb * 16 + ((lane >> 5) << 3);
  const float* src = (e < 16) ? (expert_W + (size_t)e * 65536) : share_W;
  unsigned int p[4];
#pragma unroll
  for (int j = 0; j < 4; j++) {
    float f0 = src[(size_t)(k0 + 2 * j) * 256 + d];
    float f1 = src[(size_t)(k0 + 2 * j + 1) * 256 + d];
    p[j] = (unsigned int)f2bf(f0) | ((unsigned int)f2bf(f1) << 16);
  }
  wp[g] = make_uint4(p[0], p[1], p[2], p[3]);
}

// Kernel 2 (unchanged from R3): 512 threads = 8 waves x 8 tokens; gate_W
// quarter hoisted into 16 float4 VGPRs per lane; dot accumulator split 4-way.
__global__ __launch_bounds__(512, 2) void gate_kernel(
    const float* __restrict__ inputs, const float* __restrict__ conv_out,
    const float* __restrict__ domain_emb, const float* __restrict__ gate_W,
    const float* __restrict__ gate_b, const float* __restrict__ ln_gamma,
    const float* __restrict__ ln_beta, uint4* __restrict__ apack,
    float* __restrict__ combine, float* __restrict__ frac_part) {
  __shared__ __align__(16) unsigned short atile[64 * 256]; // 32 KB xor-swizzled
  __shared__ __align__(16) float gwT[16 * 260];            // [e][c], pad 260
  __shared__ float route[8][256];                          // per-wave private rows
  __shared__ float fred[2][8][16];
  int t = threadIdx.x, b = blockIdx.x;
  int w = t >> 6, l = t & 63;

  // stage gate_W transposed: gwT[e*260 + c] = gate_W[c*16 + e]
  for (int i = 0; i < 8; i++) {
    int idx = i * 512 + t;
    gwT[(idx & 15) * 260 + (idx >> 4)] = gate_W[idx];
  }

  for (int i = 0; i < 4; i++) {
    int idx = i * 512 + t;
    int row = idx >> 5;
    int j = idx & 31;
    const float4* src = (const float4*)(inputs + ((size_t)b * 64 + row) * 256 + j * 8);
    float4 f0 = src[0], f1 = src[1];
    unsigned int p0 = (unsigned int)f2bf(f0.x) | ((unsigned int)f2bf(f0.y) << 16);
    unsigned int p1 = (unsigned int)f2bf(f0.z) | ((unsigned int)f2bf(f0.w) << 16);
    unsigned int p2 = (unsigned int)f2bf(f1.x) | ((unsigned int)f2bf(f1.y) << 16);
    unsigned int p3 = (unsigned int)f2bf(f1.z) | ((unsigned int)f2bf(f1.w) << 16);
    int s = j ^ (row & 31);
    *(uint4*)(atile + (row * 32 + s) * 8) = make_uint4(p0, p1, p2, p3);
  }
  __syncthreads();
  for (int i = 0; i < 4; i++) {
    int L = i * 512 + t;
    int ll = L & 63;
    int mb = (L >> 6) & 1, kb = L >> 7;
    int row = mb * 32 + (ll & 31);
    int j = kb * 2 + (ll >> 5);
    int s = j ^ (row & 31);
    apack[(size_t)b * 2048 + L] = *(const uint4*)(atile + (row * 32 + s) * 8);
  }

  int lc = l * 4;
  float4 g4 = *(const float4*)(ln_gamma + lc);
  float4 be4 = *(const float4*)(ln_beta + lc);
  float4 de4 = *(const float4*)(domain_emb + lc);
  int e = l & 15, q = l >> 4;
  float gb = gate_b[e];
  float psel = 0.f, pw = 0.f;

  // hoist this lane's gate-weight quarter into registers
  float4 gwreg[16];
#pragma unroll
  for (int ii = 0; ii < 16; ii++)
    gwreg[ii] = *(const float4*)&gwT[e * 260 + q * 64 + ii * 4];

  int n0 = b * 64 + w * 8;
  float4 x = *(const float4*)(conv_out + (size_t)n0 * 256 + lc);
  for (int i = 0; i < 8; i++) {
    // prefetch next token's row (wraps at i==7; value unused)
    float4 xn = *(const float4*)(conv_out + (size_t)(n0 + ((i + 1) & 7)) * 256 + lc);

    float s1 = x.x + x.y + x.z + x.w;
#pragma unroll
    for (int off = 1; off < 64; off <<= 1) s1 += __shfl_xor(s1, off);
    float mu = s1 * (1.f / 256.f);
    float dx = x.x - mu, dy = x.y - mu, dz = x.z - mu, dw = x.w - mu;
    float s2 = dx * dx + dy * dy + dz * dz + dw * dw;
#pragma unroll
    for (int off = 1; off < 64; off <<= 1) s2 += __shfl_xor(s2, off);
    float rstd = rsqrtf(s2 * (1.f / 256.f) + 1e-5f);
    float4 r;
    r.x = dx * rstd * g4.x + be4.x + de4.x;
    r.y = dy * rstd * g4.y + be4.y + de4.y;
    r.z = dz * rstd * g4.z + be4.z + de4.z;
    r.w = dw * rstd * g4.w + be4.w + de4.w;
    *(float4*)(&route[w][lc]) = r;
    // route[w] is wave-private: wave-local fence instead of block barrier
    asm volatile("s_waitcnt lgkmcnt(0)" ::: "memory");
    __builtin_amdgcn_wave_barrier();

    // logit: lane (q,e) dots channels [q*64, q*64+64) against reg-resident gw
    float a0 = 0.f, a1 = 0.f, a2 = 0.f, a3 = 0.f;
#pragma unroll
    for (int ii = 0; ii < 16; ii += 4) {
      float4 r0 = *(const float4*)(&route[w][q * 64 + (ii + 0) * 4]);
      float4 r1 = *(const float4*)(&route[w][q * 64 + (ii + 1) * 4]);
      float4 r2 = *(const float4*)(&route[w][q * 64 + (ii + 2) * 4]);
      float4 r3 = *(const float4*)(&route[w][q * 64 + (ii + 3) * 4]);
      a0 += r0.x * gwreg[ii + 0].x + r0.y * gwreg[ii + 0].y + r0.z * gwreg[ii + 0].z + r0.w * gwreg[ii + 0].w;
      a1 += r1.x * gwreg[ii + 1].x + r1.y * gwreg[ii + 1].y + r1.z * gwreg[ii + 1].z + r1.w * gwreg[ii + 1].w;
      a2 += r2.x * gwreg[ii + 2].x + r2.y * gwreg[ii + 2].y + r2.z * gwreg[ii + 2].z + r2.w * gwreg[ii + 2].w;
      a3 += r3.x * gwreg[ii + 3].x + r3.y * gwreg[ii + 3].y + r3.z * gwreg[ii + 3].z + r3.w * gwreg[ii + 3].w;
    }
    float acc = (a0 + a1) + (a2 + a3);
    acc += __shfl_xor(acc, 16);
    acc += __shfl_xor(acc, 32);
    float logit = acc + gb;

    float m = logit;
#pragma unroll
    for (int off = 1; off < 16; off <<= 1) m = fmaxf(m, __shfl_xor(m, off));
    float p = expf(logit - m);
    float sum = p;
#pragma unroll
    for (int off = 1; off < 16; off <<= 1) sum += __shfl_xor(sum, off);
    float wv = p / sum;

    float et = -wv * logf(wv + 1e-12f);
    float ent = et;
#pragma unroll
    for (int off = 1; off < 16; off <<= 1) ent += __shfl_xor(ent, off);
    float kf = ceilf(1.f + ent * (15.f / 2.7725887f));
    int k = (int)kf;
    k = max(1, min(16, k));

    int base = l & 48;
    int rank = 0;
#pragma unroll
    for (int j = 0; j < 16; j++) {
      float wj = __shfl(wv, base + j);
      rank += (wj > wv) || (wj == wv && j < e);
    }
    int sel = rank < k;
    float cmb = sel ? wv : 0.f;
    int n = n0 + i;
    if (l < 16) combine[(size_t)n * 16 + e] = cmb;
    psel += (float)sel;
    pw += wv;

    x = xn;
  }

  if (l < 16) { fred[0][w][l] = psel; fred[1][w][l] = pw; }
  __syncthreads();
  if (t < 32) {
    int kind = t >> 4, ee = t & 15;
    float v = 0.f;
#pragma unroll
    for (int ww = 0; ww < 8; ww++) v += fred[kind][ww][ee];
    frac_part[b * 32 + t] = v;
  }
}

// ---- kernel 3 helpers (v6) ----
// prefetch B-frags for slot (e,q) of this wave directly global->VGPR.
// we = wpack + e*8192 + dbp*2*1024 + l (per-lane); frag (kbl,d) at
// we + d*1024 + (q*4+kbl)*64. Perfectly coalesced 1 KB lines, L1/L2-served.
static __device__ __forceinline__ void pref_b(
    uint4 (&breg)[8], const uint4* __restrict__ we, int q) {
#pragma unroll
  for (int f = 0; f < 8; f++) {
    int kbl = f >> 1, d = f & 1;
    breg[f] = we[(size_t)d * 1024 + (q * 4 + kbl) * 64];
  }
}

// one K-quarter slot of MFMAs: A-frags from LDS (read-only after init sync),
// B-frags from registers. `first` compile-time-folds the zero-C init.
static __device__ __forceinline__ void slot_mfma(
    f32x16 (&tacc)[2][2], const f32x16& zc, const uint4* __restrict__ ab,
    const uint4 (&breg)[8], int q, bool first) {
  __builtin_amdgcn_s_setprio(1);
#pragma unroll
  for (int kbl = 0; kbl < 4; kbl++) {
    short8 a0 = BC8(ab[(q * 4 + kbl) * 256]);
    short8 a1 = BC8(ab[(q * 4 + kbl) * 256 + 64]);
    short8 b0 = BC8(breg[kbl * 2 + 0]);
    short8 b1 = BC8(breg[kbl * 2 + 1]);
    if (first && kbl == 0) {
      tacc[0][0] = MFMA32(a0, b0, zc);
      tacc[0][1] = MFMA32(a0, b1, zc);
      tacc[1][0] = MFMA32(a1, b0, zc);
      tacc[1][1] = MFMA32(a1, b1, zc);
    } else {
      tacc[0][0] = MFMA32(a0, b0, tacc[0][0]);
      tacc[0][1] = MFMA32(a0, b1, tacc[0][1]);
      tacc[1][0] = MFMA32(a1, b0, tacc[1][0]);
      tacc[1][1] = MFMA32(a1, b1, tacc[1][1]);
    }
  }
  __builtin_amdgcn_s_setprio(0);
}

// Kernel 3 (v6, resubmission — R4 failure was container-level, not kernel):
// barrier-free main loop. Diagnosis R3: LDS pipe was the critical resource
// (~1700 cyc/slot vs MFMA 1033): B made a pointless HBM/L2 -> LDS -> VGPR
// round-trip with 2x-redundant reads. Fix: B loads directly global->VGPR
// (L1/L2-served; per-slot working set 32 KB), double-buffered bregA/bregB
// with explicit prefetch of slot s+1 issued before slot s's MFMA cluster
// (overlap by construction; compiler emits counted vmcnt). A stays in LDS
// (read-only after one initial __syncthreads), so the main loop has NO
// barriers: waves free-run and desync; setprio (T5) arbitrates. LDS: 72 KB
// (atile 64 + wtile 8). e-outer/q-inner retained (scale-add once/expert).
__global__ __launch_bounds__(512, 2) void moe_gemm_kernel(
    const uint4* __restrict__ apack, const uint4* __restrict__ wpack,
    const float* __restrict__ combine, const float* __restrict__ expert_b,
    const float* __restrict__ share_b, float* __restrict__ out) {
  extern __shared__ __align__(16) char smem[];
  uint4* atile = (uint4*)smem;              // 4096 uint4 = 64 KB
  float* wtile = (float*)(smem + 65536);    // [e][row] 16*128 fp32 = 8 KB

  int t = threadIdx.x, b = blockIdx.x;
  int w = t >> 6, l = t & 63;
  int mbp = w >> 2;      // 0..1 -> rows (mbp*2+{0,1})*32
  int dbp = w & 3;       // 0..3 -> cols (dbp*2+{0,1})*32

  // ---- initial stages ----
  // A: 64 line-groups (kb 0..15 x mb 0..3), 8 per wave, from two 64-tok tiles
#pragma unroll
  for (int i = 0; i < 8; i++) {
    int g = w * 8 + i;
    int kb = g >> 2, mb = g & 3;
    const uint4* src = apack + ((size_t)(2 * b + (mb >> 1)) * 2048 + (size_t)(kb * 2 + (mb & 1)) * 64 + l);
    GLD16(atile + g * 64, src);
  }
  // wtile transposed stage: combine[tok][e] -> wtile[e*128 + tok]
  {
    const float* cg = combine + (size_t)b * 2048;
#pragma unroll
    for (int i = 0; i < 4; i++) {
      int idx = i * 512 + t;
      wtile[(idx & 15) * 128 + (idx >> 4)] = cg[idx];
    }
  }
  __syncthreads();   // drains GLD16 (vmcnt) + wtile ds_writes (lgkmcnt)

  f32x16 facc[2][2];
#pragma unroll
  for (int mi = 0; mi < 2; mi++)
#pragma unroll
    for (int d = 0; d < 2; d++)
#pragma unroll
      for (int r = 0; r < 16; r++) facc[mi][d][r] = 0.f;
  f32x16 zc;
#pragma unroll
  for (int r = 0; r < 16; r++) zc[r] = 0.f;

  f32x16 tacc[2][2];
  int rowoff = (l >> 5) * 4;   // C/D layout row offset for this half-wave

  // per-lane bases
  const uint4* ab = atile + (size_t)(mbp * 2) * 64 + l;   // + (q*4+kbl)*256 + mi*64
  const uint4* wb = wpack + (size_t)(dbp * 2) * 1024 + l; // + e*8192 + d*1024 + (q*4+kbl)*64

  uint4 bregA[8], bregB[8];
  pref_b(bregA, wb, 0);   // slot (e=0, q=0)

  for (int e = 0; e < 17; e++) {
    const uint4* we = wb + (size_t)e * 8192;
    pref_b(bregB, we, 1);                       // prefetch q=1 while q=0 computes
    slot_mfma(tacc, zc, ab, bregA, 0, true);
    pref_b(bregA, we, 2);
    slot_mfma(tacc, zc, ab, bregB, 1, false);
    pref_b(bregB, we, 3);
    slot_mfma(tacc, zc, ab, bregA, 2, false);
    if (e < 16) pref_b(bregA, we + 8192, 0);    // next expert's q=0
    slot_mfma(tacc, zc, ab, bregB, 3, false);

    // scale-add full-K expert output: facc += w[row,e] * tacc (once per expert)
    if (e < 16) {
#pragma unroll
      for (int mi = 0; mi < 2; mi++)
#pragma unroll
        for (int rg = 0; rg < 4; rg++) {
          float4 w4 = *(const float4*)&wtile[e * 128 + (mbp * 2 + mi) * 32 + 8 * rg + rowoff];
          float wj[4] = {w4.x, w4.y, w4.z, w4.w};
#pragma unroll
          for (int j = 0; j < 4; j++) {
            facc[mi][0][rg * 4 + j] += wj[j] * tacc[mi][0][rg * 4 + j];
            facc[mi][1][rg * 4 + j] += wj[j] * tacc[mi][1][rg * 4 + j];
          }
        }
    } else {  // shared expert, weight 1.0
#pragma unroll
      for (int mi = 0; mi < 2; mi++)
#pragma unroll
        for (int r = 0; r < 16; r++) {
          facc[mi][0][r] += tacc[mi][0][r];
          facc[mi][1][r] += tacc[mi][1][r];
        }
    }
  }

  // ---- final epilogue: bias terms + store ----
  int col = l & 31;
  int cg0 = (dbp * 2 + 0) * 32 + col;
  int cg1 = (dbp * 2 + 1) * 32 + col;
  float sb0 = share_b[cg0], sb1 = share_b[cg1];
  float eb0[16], eb1[16];
#pragma unroll
  for (int e2 = 0; e2 < 16; e2++) {
    eb0[e2] = expert_b[e2 * 256 + cg0];
    eb1[e2] = expert_b[e2 * 256 + cg1];
  }
  // facc += sum_e w[row,e] * expert_b[e,col]
#pragma unroll
  for (int e2 = 0; e2 < 16; e2++)
#pragma unroll
    for (int mi = 0; mi < 2; mi++)
#pragma unroll
      for (int rg = 0; rg < 4; rg++) {
        float4 w4 = *(const float4*)&wtile[e2 * 128 + (mbp * 2 + mi) * 32 + 8 * rg + rowoff];
        float wj[4] = {w4.x, w4.y, w4.z, w4.w};
#pragma unroll
        for (int j = 0; j < 4; j++) {
          facc[mi][0][rg * 4 + j] += wj[j] * eb0[e2];
          facc[mi][1][rg * 4 + j] += wj[j] * eb1[e2];
        }
      }
#pragma unroll
  for (int mi = 0; mi < 2; mi++)
#pragma unroll
    for (int r = 0; r < 16; r++) {
      int row = (mbp * 2 + mi) * 32 + (r & 3) + ((r >> 2) << 3) + rowoff;
      size_t n = (size_t)b * 128 + row;
      out[n * 256 + cg0] = facc[mi][0][r] + sb0;
      out[n * 256 + cg1] = facc[mi][1][r] + sb1;
    }
}

// Kernel 4: reduce balance-loss partials -> scalar at d_out[N*C]
__global__ __launch_bounds__(256) void finalize_kernel(
    const float* __restrict__ frac_part, float* __restrict__ loss_out) {
  __shared__ float acc[8][32];
  int t = threadIdx.x;
  int col = t & 31, seg = t >> 5;
  float s = 0.f;
  for (int i = seg; i < 512; i += 8) s += frac_part[i * 32 + col];
  acc[seg][col] = s;
  __syncthreads();
  if (t < 32) {
    float v = 0.f;
#pragma unroll
    for (int sg = 0; sg < 8; sg++) v += acc[sg][t];
    acc[0][t] = v;
  }
  __syncthreads();
  if (t == 0) {
    float loss = 0.f;
    for (int e = 0; e < 16; e++) {
      float ft = acc[0][e] * (1.f / 32768.f);
      float fp = acc[0][16 + e] * (1.f / 32768.f);
      loss += ft * fp;
    }
    loss_out[0] = loss * 16.f;
  }
}

extern "C" void kernel_launch(void* const* d_in, const int* in_sizes, int n_in,
                              void* d_out, int out_size, void* d_ws, size_t ws_size,
                              hipStream_t stream) {
  const float* inputs   = (const float*)d_in[0];
  const float* conv_out = (const float*)d_in[1];
  const float* demb     = (const float*)d_in[2];
  const float* share_W  = (const float*)d_in[3];
  const float* share_b  = (const float*)d_in[4];
  const float* gate_W   = (const float*)d_in[5];
  const float* gate_b   = (const float*)d_in[6];
  const float* expert_W = (const float*)d_in[7];
  const float* expert_b = (const float*)d_in[8];
  const float* ln_g     = (const float*)d_in[9];
  const float* ln_b     = (const float*)d_in[10];
  float* out = (float*)d_out;
  char* ws = (char*)d_ws;

  uint4* apack   = (uint4*)(ws);
  uint4* wpack   = (uint4*)(ws + 16777216);
  float* combine = (float*)(ws + 19005440);
  float* frac    = (float*)(ws + 21102592);

  // allow 72 KB dynamic LDS (idempotent; not a stream op, safe under capture)
  hipFuncSetAttribute((const void*)moe_gemm_kernel,
                      hipFuncAttributeMaxDynamicSharedMemorySize, 73728);

  wconvert_kernel<<<dim3(544), dim3(256), 0, stream>>>(share_W, expert_W, wpack);
  gate_kernel<<<dim3(512), dim3(512), 0, stream>>>(inputs, conv_out, demb, gate_W,
                                                   gate_b, ln_g, ln_b, apack, combine, frac);
  moe_gemm_kernel<<<dim3(256), dim3(512), 73728, stream>>>(apack, wpack, combine,
                                                           expert_b, share_b, out);
  finalize_kernel<<<dim3(1), dim3(256), 0, stream>>>(frac, out + 8388608);
}